// Round 9
// baseline (866.612 us; speedup 1.0000x reference)
//
#include <hip/hip_runtime.h>

#define IN_F 4096
#define OUT_F 11008

typedef __attribute__((ext_vector_type(8))) short bf16x8;   // 8 bf16 (4 VGPR) MFMA operand
typedef __attribute__((ext_vector_type(4))) float f32x4;
typedef __attribute__((ext_vector_type(4))) unsigned short us4;
typedef __attribute__((ext_vector_type(8))) unsigned short us8;

__device__ __forceinline__ unsigned short f2bf(float f) {
  unsigned int u = __float_as_uint(f);
  u += 0x7FFFu + ((u >> 16) & 1u);   // RNE
  return (unsigned short)(u >> 16);
}

// ---------------- prepass 1: X fp32 -> bf16 ----------------
__global__ __launch_bounds__(256) void cvt_x(const float* __restrict__ X,
                                             unsigned short* __restrict__ Xb, int n8) {
  for (int i = blockIdx.x * blockDim.x + threadIdx.x; i < n8;
       i += gridDim.x * blockDim.x) {
    const float4 a = reinterpret_cast<const float4*>(X)[2 * i];
    const float4 b = reinterpret_cast<const float4*>(X)[2 * i + 1];
    us8 h;
    h[0] = f2bf(a.x); h[1] = f2bf(a.y); h[2] = f2bf(a.z); h[3] = f2bf(a.w);
    h[4] = f2bf(b.x); h[5] = f2bf(b.y); h[6] = f2bf(b.z); h[7] = f2bf(b.w);
    reinterpret_cast<us8*>(Xb)[i] = h;
  }
}

// ---------------- prepass 2: W nf4 packed -> bf16 (dequant once) ----------------
__global__ __launch_bounds__(256) void dequant_w(const int* __restrict__ Wp,
                                                 const float* __restrict__ Amax,
                                                 unsigned short* __restrict__ Wb, int n4) {
  __shared__ float lutS[16];
  if (threadIdx.x < 16) {
    const float lut[16] = {-1.0f, -0.6961928009986877f, -0.5250730514526367f,
        -0.39491719007492065f, -0.28444138169288635f, -0.18477343022823334f,
        -0.08820830285549164f, 0.0f, 0.07107656449079514f, 0.14263366162776947f,
        0.22430233657360077f, 0.3203405737876892f, 0.4407068192958832f,
        0.5905631184577942f, 0.796090841293335f, 1.0f};
    lutS[threadIdx.x] = lut[threadIdx.x];
  }
  __syncthreads();
  for (int i = blockIdx.x * blockDim.x + threadIdx.x; i < n4;
       i += gridDim.x * blockDim.x) {
    const int j = i * 4;
    const int row = j >> 11;
    const int coli = j & 2047;
    const float am = Amax[row * (IN_F / 64) + (coli >> 5)];
    const int4 pk = reinterpret_cast<const int4*>(Wp)[i];
    us8 h; int c;
    c = pk.x & 255; h[0] = f2bf(lutS[c & 15] * am); h[1] = f2bf(lutS[c >> 4] * am);
    c = pk.y & 255; h[2] = f2bf(lutS[c & 15] * am); h[3] = f2bf(lutS[c >> 4] * am);
    c = pk.z & 255; h[4] = f2bf(lutS[c & 15] * am); h[5] = f2bf(lutS[c >> 4] * am);
    c = pk.w & 255; h[6] = f2bf(lutS[c & 15] * am); h[7] = f2bf(lutS[c >> 4] * am);
    reinterpret_cast<us8*>(Wb)[i] = h;
  }
}

// ---------------- main GEMM: 256x256, BK=64, dbuf-2, 1 barrier/tile ----------------
#define MF(a, b, c) __builtin_amdgcn_mfma_f32_16x16x32_bf16(a, b, c, 0, 0, 0)
#define GLDS(src, dst) __builtin_amdgcn_global_load_lds( \
    (const __attribute__((address_space(1))) void*)(src), \
    (__attribute__((address_space(3))) void*)(dst), 16, 0, 0)
#define FENCE asm volatile("" ::: "memory")
#define BAR do { FENCE; __builtin_amdgcn_s_barrier(); FENCE; } while (0)
#define VM0 asm volatile("s_waitcnt vmcnt(0)" ::: "memory")
#define P1 __builtin_amdgcn_s_setprio(1)
#define P0 __builtin_amdgcn_s_setprio(0)

__global__ __launch_bounds__(512, 2) void gemm256(
    const unsigned short* __restrict__ A,   // (M, K) bf16
    const unsigned short* __restrict__ B,   // (N, K) bf16
    const float* __restrict__ Bias, float* __restrict__ Out, int M) {
  extern __shared__ unsigned short sm[];    // 128 KiB = 2 bufs x {A kh0,A kh1,B kh0,B kh1}
  char* const smc = (char*)sm;

  const int tid = threadIdx.x;
  const int l = tid & 63;
  const int wid = tid >> 6;

  const int Nb = OUT_F / 256;               // 43

  // Supertile order: 16 m-rows x all Nb per supertile (A window 32MB L3-resident),
  // XCD-chunked inside (bps = 16*Nb, %8==0; launcher guards Mb%16==0).
  const int bps = 16 * Nb;                  // 688
  const int pxc = bps >> 3;                 // 86
  const int i6 = (int)blockIdx.x % bps;
  const int sup = (int)blockIdx.x / bps;
  const int k = (i6 & 7) * pxc + (i6 >> 3);
  const int m0 = (sup * 16 + (k & 15)) * 256;
  const int n0 = (k >> 4) * 256;

  // read-side lane constant: logical (r,c) stored at chunk c ^ ((r>>1)&3)
  const int lv = (l & 15) * 64 + (((l >> 4) ^ ((l >> 1) & 3)) * 16);   // bytes
  const int aLane = (wid >> 2) * 8192 + lv;
  const int bLane = 32768 + (wid & 3) * 4096 + lv;

  // stage-side lane constants (inverse-swizzled global source, linear LDS dest)
  const int rq = tid >> 2;
  const int cs = (tid & 3) ^ ((tid >> 3) & 3);
  const unsigned short* gAs = A + (size_t)(m0 + rq) * IN_F + cs * 8;
  const unsigned short* gBs = B + (size_t)(n0 + rq) * IN_F + cs * 8;

#define SA(t, kh) do { \
    unsigned short* d_ = sm + (size_t)((((t) & 1) * 4096) + (kh) * 1024 + wid * 64) * 8; \
    const unsigned short* s_ = gAs + (size_t)(t) * 64 + (kh) * 32; \
    GLDS(s_, d_); GLDS(s_ + 524288, d_ + 4096); } while (0)
#define SB(t, kh) do { \
    unsigned short* d_ = sm + (size_t)((((t) & 1) * 4096) + 2048 + (kh) * 1024 + wid * 64) * 8; \
    const unsigned short* s_ = gBs + (size_t)(t) * 64 + (kh) * 32; \
    GLDS(s_, d_); GLDS(s_ + 4096, d_ + 4096); } while (0)
  // NOTE: SB second GLDS covers rows 128..255 of the n-tile: source +128 rows.
#undef SB
#define SB(t, kh) do { \
    unsigned short* d_ = sm + (size_t)((((t) & 1) * 4096) + 2048 + (kh) * 1024 + wid * 64) * 8; \
    const unsigned short* s_ = gBs + (size_t)(t) * 64 + (kh) * 32; \
    GLDS(s_, d_); GLDS(s_ + 524288, d_ + 4096); } while (0)

#define MM32(AA0, AA1, AA2, AA3, AA4, AA5, AA6, AA7, BB0, BB1, BB2, BB3) do { \
    acc[0][0]=MF(AA0,BB0,acc[0][0]); acc[0][1]=MF(AA0,BB1,acc[0][1]); \
    acc[0][2]=MF(AA0,BB2,acc[0][2]); acc[0][3]=MF(AA0,BB3,acc[0][3]); \
    acc[1][0]=MF(AA1,BB0,acc[1][0]); acc[1][1]=MF(AA1,BB1,acc[1][1]); \
    acc[1][2]=MF(AA1,BB2,acc[1][2]); acc[1][3]=MF(AA1,BB3,acc[1][3]); \
    acc[2][0]=MF(AA2,BB0,acc[2][0]); acc[2][1]=MF(AA2,BB1,acc[2][1]); \
    acc[2][2]=MF(AA2,BB2,acc[2][2]); acc[2][3]=MF(AA2,BB3,acc[2][3]); \
    acc[3][0]=MF(AA3,BB0,acc[3][0]); acc[3][1]=MF(AA3,BB1,acc[3][1]); \
    acc[3][2]=MF(AA3,BB2,acc[3][2]); acc[3][3]=MF(AA3,BB3,acc[3][3]); \
    acc[4][0]=MF(AA4,BB0,acc[4][0]); acc[4][1]=MF(AA4,BB1,acc[4][1]); \
    acc[4][2]=MF(AA4,BB2,acc[4][2]); acc[4][3]=MF(AA4,BB3,acc[4][3]); \
    acc[5][0]=MF(AA5,BB0,acc[5][0]); acc[5][1]=MF(AA5,BB1,acc[5][1]); \
    acc[5][2]=MF(AA5,BB2,acc[5][2]); acc[5][3]=MF(AA5,BB3,acc[5][3]); \
    acc[6][0]=MF(AA6,BB0,acc[6][0]); acc[6][1]=MF(AA6,BB1,acc[6][1]); \
    acc[6][2]=MF(AA6,BB2,acc[6][2]); acc[6][3]=MF(AA6,BB3,acc[6][3]); \
    acc[7][0]=MF(AA7,BB0,acc[7][0]); acc[7][1]=MF(AA7,BB1,acc[7][1]); \
    acc[7][2]=MF(AA7,BB2,acc[7][2]); acc[7][3]=MF(AA7,BB3,acc[7][3]); } while (0)

  // TILE(T): VM0 | BAR | read 24 frags (both kh sets) | stage 4 units(T+1) |
  //          MFMA(set0) | MFMA(set1)       -- compiler emits counted lgkmcnt.
  // Data-ready: VM0 pre-BAR retires each wave's stages into buf[T&1]; reads post-BAR.
  // WAR: stages(T+1)->buf[(T+1)&1]; all waves' reads of that buf (tile T-1) were
  //   lgkm-consumed by MFMA(set1) register deps before they reached BAR@T.
#define KTILE(T, STG) do { \
    VM0; \
    BAR; \
    const char* LAb = smc + (((T) & 1) << 16) + aLane; \
    const char* LBb = smc + (((T) & 1) << 16) + bLane; \
    bf16x8 x0, x1, x2, x3, x4, x5, x6, x7, y0, y1, y2, y3; \
    bf16x8 u0, u1, u2, u3, u4, u5, u6, u7, v0, v1, v2, v3; \
    y0 = *(const bf16x8*)(LBb);        y1 = *(const bf16x8*)(LBb + 1024); \
    y2 = *(const bf16x8*)(LBb + 2048); y3 = *(const bf16x8*)(LBb + 3072); \
    x0 = *(const bf16x8*)(LAb);        x1 = *(const bf16x8*)(LAb + 1024); \
    x2 = *(const bf16x8*)(LAb + 2048); x3 = *(const bf16x8*)(LAb + 3072); \
    x4 = *(const bf16x8*)(LAb + 4096); x5 = *(const bf16x8*)(LAb + 5120); \
    x6 = *(const bf16x8*)(LAb + 6144); x7 = *(const bf16x8*)(LAb + 7168); \
    v0 = *(const bf16x8*)(LBb + 16384);        v1 = *(const bf16x8*)(LBb + 16384 + 1024); \
    v2 = *(const bf16x8*)(LBb + 16384 + 2048); v3 = *(const bf16x8*)(LBb + 16384 + 3072); \
    u0 = *(const bf16x8*)(LAb + 16384);        u1 = *(const bf16x8*)(LAb + 16384 + 1024); \
    u2 = *(const bf16x8*)(LAb + 16384 + 2048); u3 = *(const bf16x8*)(LAb + 16384 + 3072); \
    u4 = *(const bf16x8*)(LAb + 16384 + 4096); u5 = *(const bf16x8*)(LAb + 16384 + 5120); \
    u6 = *(const bf16x8*)(LAb + 16384 + 6144); u7 = *(const bf16x8*)(LAb + 16384 + 7168); \
    if (STG) { SA((T) + 1, 0); SB((T) + 1, 0); SA((T) + 1, 1); SB((T) + 1, 1); } \
    P1; MM32(x0, x1, x2, x3, x4, x5, x6, x7, y0, y1, y2, y3); P0; \
    P1; MM32(u0, u1, u2, u3, u4, u5, u6, u7, v0, v1, v2, v3); P0; \
  } while (0)

  f32x4 acc[8][4];
#pragma unroll
  for (int i = 0; i < 8; ++i)
#pragma unroll
    for (int j = 0; j < 4; ++j) acc[i][j] = {0.f, 0.f, 0.f, 0.f};

  // prologue: stage tile 0 (8 loads); TILE(0)'s VM0+BAR is the sync.
  SA(0, 0); SB(0, 0); SA(0, 1); SB(0, 1);

  for (int T = 0; T < 63; ++T) { KTILE(T, 1); }
  KTILE(63, 0);

  // epilogue: C = acc + bias   (C/D map: col = l&15, row = (l>>4)*4 + reg)
  const int crow = m0 + (wid >> 2) * 128 + ((l >> 4) << 2);
  const int ccol = n0 + (wid & 3) * 64 + (l & 15);
#pragma unroll
  for (int nf = 0; nf < 4; ++nf) {
    const float bv = Bias[ccol + nf * 16];
#pragma unroll
    for (int f = 0; f < 8; ++f)
#pragma unroll
      for (int rg = 0; rg < 4; ++rg)
        Out[(size_t)(crow + f * 16 + rg) * OUT_F + ccol + nf * 16] = acc[f][nf][rg] + bv;
  }
}

// ---------------- fallback: fused kernel (if ws too small / shape off) ----------------
__global__ __launch_bounds__(256, 2) void nf4_gemm_fused(
    const float* __restrict__ X, const int* __restrict__ Wp,
    const float* __restrict__ Amax, const float* __restrict__ Bias,
    float* __restrict__ Out, int M) {
  __shared__ unsigned short As[128 * 64];
  __shared__ unsigned short Bs[128 * 64];
  __shared__ float lutS[16];

  const int t = threadIdx.x;
  const int l = t & 63;
  const int wid = t >> 6;

  if (t < 16) {
    const float lut[16] = {-1.0f, -0.6961928009986877f, -0.5250730514526367f,
        -0.39491719007492065f, -0.28444138169288635f, -0.18477343022823334f,
        -0.08820830285549164f, 0.0f, 0.07107656449079514f, 0.14263366162776947f,
        0.22430233657360077f, 0.3203405737876892f, 0.4407068192958832f,
        0.5905631184577942f, 0.796090841293335f, 1.0f};
    lutS[t] = lut[t];
  }

  const int ntile = OUT_F / 128;
  const int m0 = (blockIdx.x / ntile) * 128;
  const int n0 = (blockIdx.x % ntile) * 128;

  const int ar = t >> 4;
  const int ac4 = t & 15;
  const int br = t >> 3;
  const int bg = t & 7;
  const int wm = (wid >> 1) * 64;
  const int wn = (wid & 1) * 64;

  f32x4 acc[4][4];
#pragma unroll
  for (int i = 0; i < 4; ++i)
#pragma unroll
    for (int j = 0; j < 4; ++j) acc[i][j] = {0.f, 0.f, 0.f, 0.f};

  __syncthreads();

  for (int k0 = 0; k0 < IN_F; k0 += 64) {
#pragma unroll
    for (int p = 0; p < 8; ++p) {
      const int r = p * 16 + ar;
      const float4 v = *reinterpret_cast<const float4*>(
          X + (size_t)(m0 + r) * IN_F + k0 + ac4 * 4);
      us4 h;
      h[0] = f2bf(v.x); h[1] = f2bf(v.y); h[2] = f2bf(v.z); h[3] = f2bf(v.w);
      const int byte = r * 128 + ((ac4 * 8) ^ ((r & 7) << 4));
      *reinterpret_cast<us4*>(reinterpret_cast<char*>(As) + byte) = h;
    }
#pragma unroll
    for (int p = 0; p < 4; ++p) {
      const int r = p * 32 + br;
      const float amv = Amax[(size_t)(n0 + r) * (IN_F / 64) + (k0 >> 6)];
      const int4 pk = *reinterpret_cast<const int4*>(
          Wp + (size_t)(n0 + r) * (IN_F / 2) + (k0 >> 1) + bg * 4);
      us8 h;
      {
        int c;
        c = pk.x & 255; h[0] = f2bf(lutS[c & 15] * amv); h[1] = f2bf(lutS[c >> 4] * amv);
        c = pk.y & 255; h[2] = f2bf(lutS[c & 15] * amv); h[3] = f2bf(lutS[c >> 4] * amv);
        c = pk.z & 255; h[4] = f2bf(lutS[c & 15] * amv); h[5] = f2bf(lutS[c >> 4] * amv);
        c = pk.w & 255; h[6] = f2bf(lutS[c & 15] * amv); h[7] = f2bf(lutS[c >> 4] * amv);
      }
      const int byte = r * 128 + ((bg * 16) ^ ((r & 7) << 4));
      *reinterpret_cast<us8*>(reinterpret_cast<char*>(Bs) + byte) = h;
    }
    __syncthreads();

#pragma unroll
    for (int kk = 0; kk < 64; kk += 32) {
      bf16x8 af[4], bfv[4];
      const int kb = (kk + ((l >> 4) << 3)) * 2;
#pragma unroll
      for (int i = 0; i < 4; ++i) {
        const int row = wm + i * 16 + (l & 15);
        af[i] = *reinterpret_cast<const bf16x8*>(
            reinterpret_cast<const char*>(As) + row * 128 + (kb ^ ((row & 7) << 4)));
      }
#pragma unroll
      for (int j = 0; j < 4; ++j) {
        const int row = wn + j * 16 + (l & 15);
        bfv[j] = *reinterpret_cast<const bf16x8*>(
            reinterpret_cast<const char*>(Bs) + row * 128 + (kb ^ ((row & 7) << 4)));
      }
#pragma unroll
      for (int i = 0; i < 4; ++i)
#pragma unroll
        for (int j = 0; j < 4; ++j)
          acc[i][j] = __builtin_amdgcn_mfma_f32_16x16x32_bf16(af[i], bfv[j], acc[i][j], 0, 0, 0);
    }
    __syncthreads();
  }

  const int crow0 = m0 + wm + ((l >> 4) << 2);
  const int ccol0 = n0 + wn + (l & 15);
#pragma unroll
  for (int j = 0; j < 4; ++j) {
    const float bv = Bias[ccol0 + j * 16];
#pragma unroll
    for (int i = 0; i < 4; ++i)
#pragma unroll
      for (int rg = 0; rg < 4; ++rg)
        Out[(size_t)(crow0 + i * 16 + rg) * OUT_F + ccol0 + j * 16] = acc[i][j][rg] + bv;
  }
}

extern "C" void kernel_launch(void* const* d_in, const int* in_sizes, int n_in,
                              void* d_out, int out_size, void* d_ws, size_t ws_size,
                              hipStream_t stream) {
  const float* X = (const float*)d_in[0];
  const int* Wp = (const int*)d_in[1];
  const float* Amax = (const float*)d_in[2];
  const float* Bias = (const float*)d_in[3];
  float* Out = (float*)d_out;

  const int M = in_sizes[0] / IN_F;                       // 8192
  const size_t needX = (size_t)M * IN_F * 2;
  const size_t needW = (size_t)OUT_F * IN_F * 2;
  const int grid256 = (M / 256) * (OUT_F / 256);          // 32*43 = 1376

  if (ws_size >= needX + needW && (M % 4096) == 0) {      // Mb%16==0 for supertile map
    unsigned short* Xb = (unsigned short*)d_ws;
    unsigned short* Wb = Xb + (size_t)M * IN_F;
    (void)hipFuncSetAttribute(reinterpret_cast<const void*>(gemm256),
                              hipFuncAttributeMaxDynamicSharedMemorySize, 131072);
    cvt_x<<<2048, 256, 0, stream>>>(X, Xb, M * (IN_F / 8));
    dequant_w<<<2048, 256, 0, stream>>>(Wp, Amax, Wb, OUT_F * (IN_F / 8));
    gemm256<<<grid256, 512, 131072, stream>>>(Xb, Wb, Bias, Out, M);
  } else {
    const int grid = (M / 128) * (OUT_F / 128);
    nf4_gemm_fused<<<grid, 256, 0, stream>>>(X, Wp, Amax, Bias, Out, M);
  }
}

// Round 10
// 805.391 us; speedup vs baseline: 1.0760x; 1.0760x over previous
//
#include <hip/hip_runtime.h>

#define IN_F 4096
#define OUT_F 11008

typedef __attribute__((ext_vector_type(8))) short bf16x8;   // 8 bf16 (4 VGPR) MFMA operand
typedef __attribute__((ext_vector_type(4))) float f32x4;
typedef __attribute__((ext_vector_type(4))) unsigned short us4;
typedef __attribute__((ext_vector_type(8))) unsigned short us8;

__device__ __forceinline__ unsigned short f2bf(float f) {
  unsigned int u = __float_as_uint(f);
  u += 0x7FFFu + ((u >> 16) & 1u);   // RNE
  return (unsigned short)(u >> 16);
}

// ---------------- prepass 1: X fp32 -> bf16 ----------------
__global__ __launch_bounds__(256) void cvt_x(const float* __restrict__ X,
                                             unsigned short* __restrict__ Xb, int n8) {
  for (int i = blockIdx.x * blockDim.x + threadIdx.x; i < n8;
       i += gridDim.x * blockDim.x) {
    const float4 a = reinterpret_cast<const float4*>(X)[2 * i];
    const float4 b = reinterpret_cast<const float4*>(X)[2 * i + 1];
    us8 h;
    h[0] = f2bf(a.x); h[1] = f2bf(a.y); h[2] = f2bf(a.z); h[3] = f2bf(a.w);
    h[4] = f2bf(b.x); h[5] = f2bf(b.y); h[6] = f2bf(b.z); h[7] = f2bf(b.w);
    reinterpret_cast<us8*>(Xb)[i] = h;
  }
}

// ---------------- prepass 2: W nf4 packed -> bf16 (dequant once) ----------------
__global__ __launch_bounds__(256) void dequant_w(const int* __restrict__ Wp,
                                                 const float* __restrict__ Amax,
                                                 unsigned short* __restrict__ Wb, int n4) {
  __shared__ float lutS[16];
  if (threadIdx.x < 16) {
    const float lut[16] = {-1.0f, -0.6961928009986877f, -0.5250730514526367f,
        -0.39491719007492065f, -0.28444138169288635f, -0.18477343022823334f,
        -0.08820830285549164f, 0.0f, 0.07107656449079514f, 0.14263366162776947f,
        0.22430233657360077f, 0.3203405737876892f, 0.4407068192958832f,
        0.5905631184577942f, 0.796090841293335f, 1.0f};
    lutS[threadIdx.x] = lut[threadIdx.x];
  }
  __syncthreads();
  for (int i = blockIdx.x * blockDim.x + threadIdx.x; i < n4;
       i += gridDim.x * blockDim.x) {
    const int j = i * 4;
    const int row = j >> 11;
    const int coli = j & 2047;
    const float am = Amax[row * (IN_F / 64) + (coli >> 5)];
    const int4 pk = reinterpret_cast<const int4*>(Wp)[i];
    us8 h; int c;
    c = pk.x & 255; h[0] = f2bf(lutS[c & 15] * am); h[1] = f2bf(lutS[c >> 4] * am);
    c = pk.y & 255; h[2] = f2bf(lutS[c & 15] * am); h[3] = f2bf(lutS[c >> 4] * am);
    c = pk.z & 255; h[4] = f2bf(lutS[c & 15] * am); h[5] = f2bf(lutS[c >> 4] * am);
    c = pk.w & 255; h[6] = f2bf(lutS[c & 15] * am); h[7] = f2bf(lutS[c >> 4] * am);
    reinterpret_cast<us8*>(Wb)[i] = h;
  }
}

// ---------------- main GEMM: 256x256, BK=64, dbuf-2, 4 fine phases/K-tile ----------------
#define MF(a, b, c) __builtin_amdgcn_mfma_f32_16x16x32_bf16(a, b, c, 0, 0, 0)
#define GLDS(src, dst) __builtin_amdgcn_global_load_lds( \
    (const __attribute__((address_space(1))) void*)(src), \
    (__attribute__((address_space(3))) void*)(dst), 16, 0, 0)
#define FENCE asm volatile("" ::: "memory")
#define BAR do { FENCE; __builtin_amdgcn_s_barrier(); FENCE; } while (0)
#define VM4 asm volatile("s_waitcnt vmcnt(4)" ::: "memory")
#define VM0 asm volatile("s_waitcnt vmcnt(0)" ::: "memory")
#define P1 __builtin_amdgcn_s_setprio(1)
#define P0 __builtin_amdgcn_s_setprio(0)

__global__ __launch_bounds__(512, 2) void gemm256(
    const unsigned short* __restrict__ A,   // (M, K) bf16
    const unsigned short* __restrict__ B,   // (N, K) bf16
    const float* __restrict__ Bias, float* __restrict__ Out, int M) {
  extern __shared__ unsigned short sm[];    // 128 KiB = 2 bufs x {A kh0,A kh1,B kh0,B kh1}
  char* const smc = (char*)sm;

  const int tid = threadIdx.x;
  const int l = tid & 63;
  const int wid = tid >> 6;

  const int Nb = OUT_F / 256;               // 43

  // Supertile order: 16 m-rows x all Nb per supertile (A window 32MB L3-resident),
  // XCD-chunked inside (bps = 16*Nb, %8==0; launcher guards Mb%16==0).
  const int bps = 16 * Nb;                  // 688
  const int pxc = bps >> 3;                 // 86
  const int i6 = (int)blockIdx.x % bps;
  const int sup = (int)blockIdx.x / bps;
  const int k = (i6 & 7) * pxc + (i6 >> 3);
  const int m0 = (sup * 16 + (k & 15)) * 256;
  const int n0 = (k >> 4) * 256;

  // read-side lane constant: logical (r,c) stored at chunk c ^ ((r>>1)&3)
  const int lv = (l & 15) * 64 + (((l >> 4) ^ ((l >> 1) & 3)) * 16);   // bytes
  const int aLane = (wid >> 2) * 8192 + lv;
  const int bLane = 32768 + (wid & 3) * 4096 + lv;

  // stage-side lane constants (inverse-swizzled global source, linear LDS dest)
  const int rq = tid >> 2;
  const int cs = (tid & 3) ^ ((tid >> 3) & 3);
  const unsigned short* gAs = A + (size_t)(m0 + rq) * IN_F + cs * 8;
  const unsigned short* gBs = B + (size_t)(n0 + rq) * IN_F + cs * 8;

  // unit = 16 KiB (256 rows x 32 k) = 2 glds/thread. Layout within buf (bytes):
  //   A·kh0 @0, A·kh1 @16384, B·kh0 @32768, B·kh1 @49152; buf stride 65536.
#define SA(t, kh) do { \
    unsigned short* d_ = sm + (size_t)((((t) & 1) * 4096) + (kh) * 1024 + wid * 64) * 8; \
    const unsigned short* s_ = gAs + (size_t)(t) * 64 + (kh) * 32; \
    GLDS(s_, d_); GLDS(s_ + 524288, d_ + 4096); } while (0)
#define SB(t, kh) do { \
    unsigned short* d_ = sm + (size_t)((((t) & 1) * 4096) + 2048 + (kh) * 1024 + wid * 64) * 8; \
    const unsigned short* s_ = gBs + (size_t)(t) * 64 + (kh) * 32; \
    GLDS(s_, d_); GLDS(s_ + 524288, d_ + 4096); } while (0)

  // 16 MFMA quadrant: m-rows mb..mb+3  x  all 4 n
#define MMQ(A0, A1, A2, A3, mb) do { \
    acc[(mb)+0][0]=MF(A0,y0,acc[(mb)+0][0]); acc[(mb)+0][1]=MF(A0,y1,acc[(mb)+0][1]); \
    acc[(mb)+0][2]=MF(A0,y2,acc[(mb)+0][2]); acc[(mb)+0][3]=MF(A0,y3,acc[(mb)+0][3]); \
    acc[(mb)+1][0]=MF(A1,y0,acc[(mb)+1][0]); acc[(mb)+1][1]=MF(A1,y1,acc[(mb)+1][1]); \
    acc[(mb)+1][2]=MF(A1,y2,acc[(mb)+1][2]); acc[(mb)+1][3]=MF(A1,y3,acc[(mb)+1][3]); \
    acc[(mb)+2][0]=MF(A2,y0,acc[(mb)+2][0]); acc[(mb)+2][1]=MF(A2,y1,acc[(mb)+2][1]); \
    acc[(mb)+2][2]=MF(A2,y2,acc[(mb)+2][2]); acc[(mb)+2][3]=MF(A2,y3,acc[(mb)+2][3]); \
    acc[(mb)+3][0]=MF(A3,y0,acc[(mb)+3][0]); acc[(mb)+3][1]=MF(A3,y1,acc[(mb)+3][1]); \
    acc[(mb)+3][2]=MF(A3,y2,acc[(mb)+3][2]); acc[(mb)+3][3]=MF(A3,y3,acc[(mb)+3][3]); } while (0)

  // KTILE(T): 4 fine phases. Per phase: {reads ∥ 1 stage-unit(T+1)} | BAR | 16 MFMA | BAR.
  // VM4 before ph1/ph3 closing BAR: retires the 2 units (4 loads) issued 3-4 phases ago,
  // which are exactly the units the phases after that barrier read.        [induction ok]
  // WAR: each staged unit's region was last read >=2 barriers before the stage issues.
#define KTILE(T, STG, VMW) do { \
    const char* LAb = smc + (((T) & 1) << 16) + aLane; \
    const char* LBb = smc + (((T) & 1) << 16) + bLane; \
    bf16x8 x0, x1, x2, x3, x4, x5, x6, x7, y0, y1, y2, y3; \
    /* ---- ph0: A m0-3 kh0 + B kh0 ---- */ \
    y0 = *(const bf16x8*)(LBb);        y1 = *(const bf16x8*)(LBb + 1024); \
    y2 = *(const bf16x8*)(LBb + 2048); y3 = *(const bf16x8*)(LBb + 3072); \
    x0 = *(const bf16x8*)(LAb);        x1 = *(const bf16x8*)(LAb + 1024); \
    x2 = *(const bf16x8*)(LAb + 2048); x3 = *(const bf16x8*)(LAb + 3072); \
    if (STG) SA((T) + 1, 0); \
    BAR; P1; MMQ(x0, x1, x2, x3, 0); P0; BAR; \
    /* ---- ph1: A m4-7 kh0 (B regs reused) ---- */ \
    x4 = *(const bf16x8*)(LAb + 4096); x5 = *(const bf16x8*)(LAb + 5120); \
    x6 = *(const bf16x8*)(LAb + 6144); x7 = *(const bf16x8*)(LAb + 7168); \
    if (STG) SB((T) + 1, 0); \
    BAR; P1; MMQ(x4, x5, x6, x7, 4); P0; VMW; BAR; \
    /* ---- ph2: A m0-3 kh1 + B kh1 ---- */ \
    y0 = *(const bf16x8*)(LBb + 16384);        y1 = *(const bf16x8*)(LBb + 16384 + 1024); \
    y2 = *(const bf16x8*)(LBb + 16384 + 2048); y3 = *(const bf16x8*)(LBb + 16384 + 3072); \
    x0 = *(const bf16x8*)(LAb + 16384);        x1 = *(const bf16x8*)(LAb + 16384 + 1024); \
    x2 = *(const bf16x8*)(LAb + 16384 + 2048); x3 = *(const bf16x8*)(LAb + 16384 + 3072); \
    if (STG) SA((T) + 1, 1); \
    BAR; P1; MMQ(x0, x1, x2, x3, 0); P0; BAR; \
    /* ---- ph3: A m4-7 kh1 ---- */ \
    x4 = *(const bf16x8*)(LAb + 16384 + 4096); x5 = *(const bf16x8*)(LAb + 16384 + 5120); \
    x6 = *(const bf16x8*)(LAb + 16384 + 6144); x7 = *(const bf16x8*)(LAb + 16384 + 7168); \
    if (STG) SB((T) + 1, 1); \
    BAR; P1; MMQ(x4, x5, x6, x7, 4); P0; VMW; BAR; \
  } while (0)

  f32x4 acc[8][4];
#pragma unroll
  for (int i = 0; i < 8; ++i)
#pragma unroll
    for (int j = 0; j < 4; ++j) acc[i][j] = {0.f, 0.f, 0.f, 0.f};

  // prologue: tile-0 units in read order; VM4 retires {A·kh0, B·kh0}; BAR publishes.
  SA(0, 0); SB(0, 0); SA(0, 1); SB(0, 1);
  VM4;
  BAR;

  for (int T = 0; T < 63; ++T) { KTILE(T, 1, VM4); }
  KTILE(63, 0, VM0);

  // epilogue: C = acc + bias   (C/D map: col = l&15, row = (l>>4)*4 + reg)
  const int crow = m0 + (wid >> 2) * 128 + ((l >> 4) << 2);
  const int ccol = n0 + (wid & 3) * 64 + (l & 15);
#pragma unroll
  for (int nf = 0; nf < 4; ++nf) {
    const float bv = Bias[ccol + nf * 16];
#pragma unroll
    for (int f = 0; f < 8; ++f)
#pragma unroll
      for (int rg = 0; rg < 4; ++rg)
        Out[(size_t)(crow + f * 16 + rg) * OUT_F + ccol + nf * 16] = acc[f][nf][rg] + bv;
  }
}

// ---------------- fallback: fused kernel (if ws too small / shape off) ----------------
__global__ __launch_bounds__(256, 2) void nf4_gemm_fused(
    const float* __restrict__ X, const int* __restrict__ Wp,
    const float* __restrict__ Amax, const float* __restrict__ Bias,
    float* __restrict__ Out, int M) {
  __shared__ unsigned short As[128 * 64];
  __shared__ unsigned short Bs[128 * 64];
  __shared__ float lutS[16];

  const int t = threadIdx.x;
  const int l = t & 63;
  const int wid = t >> 6;

  if (t < 16) {
    const float lut[16] = {-1.0f, -0.6961928009986877f, -0.5250730514526367f,
        -0.39491719007492065f, -0.28444138169288635f, -0.18477343022823334f,
        -0.08820830285549164f, 0.0f, 0.07107656449079514f, 0.14263366162776947f,
        0.22430233657360077f, 0.3203405737876892f, 0.4407068192958832f,
        0.5905631184577942f, 0.796090841293335f, 1.0f};
    lutS[t] = lut[t];
  }

  const int ntile = OUT_F / 128;
  const int m0 = (blockIdx.x / ntile) * 128;
  const int n0 = (blockIdx.x % ntile) * 128;

  const int ar = t >> 4;
  const int ac4 = t & 15;
  const int br = t >> 3;
  const int bg = t & 7;
  const int wm = (wid >> 1) * 64;
  const int wn = (wid & 1) * 64;

  f32x4 acc[4][4];
#pragma unroll
  for (int i = 0; i < 4; ++i)
#pragma unroll
    for (int j = 0; j < 4; ++j) acc[i][j] = {0.f, 0.f, 0.f, 0.f};

  __syncthreads();

  for (int k0 = 0; k0 < IN_F; k0 += 64) {
#pragma unroll
    for (int p = 0; p < 8; ++p) {
      const int r = p * 16 + ar;
      const float4 v = *reinterpret_cast<const float4*>(
          X + (size_t)(m0 + r) * IN_F + k0 + ac4 * 4);
      us4 h;
      h[0] = f2bf(v.x); h[1] = f2bf(v.y); h[2] = f2bf(v.z); h[3] = f2bf(v.w);
      const int byte = r * 128 + ((ac4 * 8) ^ ((r & 7) << 4));
      *reinterpret_cast<us4*>(reinterpret_cast<char*>(As) + byte) = h;
    }
#pragma unroll
    for (int p = 0; p < 4; ++p) {
      const int r = p * 32 + br;
      const float amv = Amax[(size_t)(n0 + r) * (IN_F / 64) + (k0 >> 6)];
      const int4 pk = *reinterpret_cast<const int4*>(
          Wp + (size_t)(n0 + r) * (IN_F / 2) + (k0 >> 1) + bg * 4);
      us8 h;
      {
        int c;
        c = pk.x & 255; h[0] = f2bf(lutS[c & 15] * amv); h[1] = f2bf(lutS[c >> 4] * amv);
        c = pk.y & 255; h[2] = f2bf(lutS[c & 15] * amv); h[3] = f2bf(lutS[c >> 4] * amv);
        c = pk.z & 255; h[4] = f2bf(lutS[c & 15] * amv); h[5] = f2bf(lutS[c >> 4] * amv);
        c = pk.w & 255; h[6] = f2bf(lutS[c & 15] * amv); h[7] = f2bf(lutS[c >> 4] * amv);
      }
      const int byte = r * 128 + ((bg * 16) ^ ((r & 7) << 4));
      *reinterpret_cast<us8*>(reinterpret_cast<char*>(Bs) + byte) = h;
    }
    __syncthreads();

#pragma unroll
    for (int kk = 0; kk < 64; kk += 32) {
      bf16x8 af[4], bfv[4];
      const int kb = (kk + ((l >> 4) << 3)) * 2;
#pragma unroll
      for (int i = 0; i < 4; ++i) {
        const int row = wm + i * 16 + (l & 15);
        af[i] = *reinterpret_cast<const bf16x8*>(
            reinterpret_cast<const char*>(As) + row * 128 + (kb ^ ((row & 7) << 4)));
      }
#pragma unroll
      for (int j = 0; j < 4; ++j) {
        const int row = wn + j * 16 + (l & 15);
        bfv[j] = *reinterpret_cast<const bf16x8*>(
            reinterpret_cast<const char*>(Bs) + row * 128 + (kb ^ ((row & 7) << 4)));
      }
#pragma unroll
      for (int i = 0; i < 4; ++i)
#pragma unroll
        for (int j = 0; j < 4; ++j)
          acc[i][j] = __builtin_amdgcn_mfma_f32_16x16x32_bf16(af[i], bfv[j], acc[i][j], 0, 0, 0);
    }
    __syncthreads();
  }

  const int crow0 = m0 + wm + ((l >> 4) << 2);
  const int ccol0 = n0 + wn + (l & 15);
#pragma unroll
  for (int j = 0; j < 4; ++j) {
    const float bv = Bias[ccol0 + j * 16];
#pragma unroll
    for (int i = 0; i < 4; ++i)
#pragma unroll
      for (int rg = 0; rg < 4; ++rg)
        Out[(size_t)(crow0 + i * 16 + rg) * OUT_F + ccol0 + j * 16] = acc[i][j][rg] + bv;
  }
}

extern "C" void kernel_launch(void* const* d_in, const int* in_sizes, int n_in,
                              void* d_out, int out_size, void* d_ws, size_t ws_size,
                              hipStream_t stream) {
  const float* X = (const float*)d_in[0];
  const int* Wp = (const int*)d_in[1];
  const float* Amax = (const float*)d_in[2];
  const float* Bias = (const float*)d_in[3];
  float* Out = (float*)d_out;

  const int M = in_sizes[0] / IN_F;                       // 8192
  const size_t needX = (size_t)M * IN_F * 2;
  const size_t needW = (size_t)OUT_F * IN_F * 2;
  const int grid256 = (M / 256) * (OUT_F / 256);          // 32*43 = 1376

  if (ws_size >= needX + needW && (M % 4096) == 0) {      // Mb%16==0 for supertile map
    unsigned short* Xb = (unsigned short*)d_ws;
    unsigned short* Wb = Xb + (size_t)M * IN_F;
    (void)hipFuncSetAttribute(reinterpret_cast<const void*>(gemm256),
                              hipFuncAttributeMaxDynamicSharedMemorySize, 131072);
    cvt_x<<<2048, 256, 0, stream>>>(X, Xb, M * (IN_F / 8));
    dequant_w<<<2048, 256, 0, stream>>>(Wp, Amax, Wb, OUT_F * (IN_F / 8));
    gemm256<<<grid256, 512, 131072, stream>>>(Xb, Wb, Bias, Out, M);
  } else {
    const int grid = (M / 128) * (OUT_F / 128);
    nf4_gemm_fused<<<grid, 256, 0, stream>>>(X, Wp, Amax, Bias, Out, M);
  }
}